// Round 3
// baseline (539.260 us; speedup 1.0000x reference)
//
#include <hip/hip_runtime.h>
#include <cstdint>

typedef float f32x2 __attribute__((ext_vector_type(2)));
typedef float f32x4 __attribute__((ext_vector_type(4)));

// Problem constants (match reference)
constexpr int N_TOK = 32768;
constexpr int DIM   = 1024;
constexpr int NEXP  = 64;
constexpr float CAPACITY = 40960.0f;   // int(1.25 * 32768)
constexpr float EPS_DEN  = 1e-6f;

// Persistent device scratch.
// g_sums: [0..63]=denom, [64..127]=importance, [128..191]=load
__device__ float  g_sums[256];
__device__ float4 g_rec[N_TOK];   // per-row: {raw1, raw2, idx1, idx2}

__global__ void init_sums() {
    if (threadIdx.x < 192) g_sums[threadIdx.x] = 0.0f;
}

// ---------------------------------------------------------------------------
// Kernel 1: fused GEMM (x @ w^T + b) + softmax + top-2 + per-expert sums
//   lane == expert. block = 256 (4 waves), wave owns RPW=8 rows.
//   w tile double-buffered in LDS; x read via wave-uniform scalar loads
//   (zero VALU / zero LDS cost); packed f32 FMA for the inner product.
// ---------------------------------------------------------------------------
#define WAVES 4
#define RPW   8
#define ROWS_PER_BLK (WAVES * RPW)   // 32
#define BK    64                     // K-tile (floats)
#define NKT   (DIM / BK)             // 16

__global__ __launch_bounds__(256, 4)
void gate_main(const float* __restrict__ x,
               const float* __restrict__ wg,
               const float* __restrict__ bg) {
    // [buf][k4][expert], expert XOR-swizzled by k4&7 (measured 0 conflicts)
    __shared__ f32x4 wt[2][BK / 4][NEXP];   // 32 KB

    const int tid  = threadIdx.x;
    const int lane = tid & 63;
    const int wv   = __builtin_amdgcn_readfirstlane(tid >> 6);  // wave-uniform
    const int row0 = blockIdx.x * ROWS_PER_BLK + wv * RPW;

    const f32x4* w4 = (const f32x4*)wg;
    f32x4 st[4];

    // ---- prologue: stage tile 0 ----
#pragma unroll
    for (int i = 0; i < 4; ++i) {
        int j = tid + 256 * i; int e = j >> 4; int k4 = j & 15;
        st[i] = w4[(size_t)e * (DIM / 4) + k4];
    }
#pragma unroll
    for (int i = 0; i < 4; ++i) {
        int j = tid + 256 * i; int e = j >> 4; int k4 = j & 15;
        wt[0][k4][e ^ (k4 & 7)] = st[i];
    }
    __syncthreads();

    f32x2 acc[RPW];
#pragma unroll
    for (int r = 0; r < RPW; ++r) acc[r] = (f32x2){0.0f, 0.0f};

    const float* xbase = x + (size_t)row0 * DIM;   // wave-uniform pointer

    for (int kt = 0; kt < NKT; ++kt) {
        const int cb = kt & 1;
        // issue next tile's global loads (in flight across the compute phase)
        if (kt + 1 < NKT) {
#pragma unroll
            for (int i = 0; i < 4; ++i) {
                int j = tid + 256 * i; int e = j >> 4; int k4 = j & 15;
                st[i] = w4[(size_t)e * (DIM / 4) + (kt + 1) * (BK / 4) + k4];
            }
        }
        // compute on current buffer
#pragma unroll
        for (int k4 = 0; k4 < BK / 4; ++k4) {
            f32x4 wv4 = wt[cb][k4][lane ^ (k4 & 7)];
            f32x2 wlo = {wv4.x, wv4.y};
            f32x2 whi = {wv4.z, wv4.w};
#pragma unroll
            for (int r = 0; r < RPW; ++r) {
                // wave-uniform address -> scalar (SMEM) load / broadcast VMEM
                const f32x2* xp = (const f32x2*)(xbase + (size_t)r * DIM
                                                 + kt * BK + k4 * 4);
                acc[r] = __builtin_elementwise_fma(xp[0], wlo, acc[r]);
                acc[r] = __builtin_elementwise_fma(xp[1], whi, acc[r]);
            }
        }
        // swap buffers: write prefetched tile
        if (kt + 1 < NKT) {
            __syncthreads();
#pragma unroll
            for (int i = 0; i < 4; ++i) {
                int j = tid + 256 * i; int e = j >> 4; int k4 = j & 15;
                wt[cb ^ 1][k4][e ^ (k4 & 7)] = st[i];
            }
            __syncthreads();
        }
    }

    // ---- epilogue: softmax + top-2 per row, local per-expert accumulation ----
    const float b = bg[lane];
    float den_acc = 0.0f, imp_acc = 0.0f, load_acc = 0.0f;

    for (int r = 0; r < RPW; ++r) {
        float v = acc[r].x + acc[r].y + b;

        float m = v;
#pragma unroll
        for (int off = 32; off; off >>= 1) m = fmaxf(m, __shfl_xor(m, off));

        float ev = expf(v - m);
        float s = ev;
#pragma unroll
        for (int off = 32; off; off >>= 1) s += __shfl_xor(s, off);

        float raw = ev / s;   // softmax score for expert `lane`

        // top-1: lowest lane index attaining the max (matches jax top_k ties)
        unsigned long long mk1 = __ballot(v == m);
        int idx1 = __ffsll(mk1) - 1;

        float v2 = (lane == idx1) ? -INFINITY : v;
        float m2 = v2;
#pragma unroll
        for (int off = 32; off; off >>= 1) m2 = fmaxf(m2, __shfl_xor(m2, off));
        unsigned long long mk2 = __ballot(v2 == m2);
        int idx2 = __ffsll(mk2) - 1;

        bool sel = (lane == idx1) || (lane == idx2);
        imp_acc += raw;
        if (sel) { den_acc += raw; load_acc += 1.0f; }

        float raw1 = __shfl(raw, idx1);
        float raw2 = __shfl(raw, idx2);
        if (lane == 0) {
            g_rec[row0 + r] = make_float4(raw1, raw2,
                                          __int_as_float(idx1), __int_as_float(idx2));
        }
    }

    atomicAdd(&g_sums[lane],       den_acc);
    atomicAdd(&g_sums[64 + lane],  imp_acc);
    atomicAdd(&g_sums[128 + lane], load_acc);
}

// ---------------------------------------------------------------------------
// Kernel 2: finalize + scatter fused.
//   scale[e] = capacity/(denom[e]+eps) computed per block (768 B read);
//   block 0 also emits the aux-loss scalar. 16 threads/row -> float4 stores.
// ---------------------------------------------------------------------------
__global__ __launch_bounds__(256)
void scatter_out(float* __restrict__ out) {
    __shared__ float scale_s[NEXP];
    int tid = threadIdx.x;
    if (tid < NEXP) {
        float den = g_sums[tid];
        scale_s[tid] = CAPACITY / (den + EPS_DEN);
        if (blockIdx.x == 0) {
            float prod = g_sums[64 + tid] * g_sums[128 + tid];
#pragma unroll
            for (int off = 32; off; off >>= 1) prod += __shfl_xor(prod, off);
            if (tid == 0) {
                // aux = 0.01 * mean_e(imp*load) * 64^2 = 0.64 * sum / N^2
                out[(size_t)N_TOK * NEXP] =
                    0.64f * prod / ((float)N_TOK * (float)N_TOK);
            }
        }
    }
    __syncthreads();

    int row = blockIdx.x * 16 + (tid >> 4);
    int g   = tid & 15;

    float4 rec = g_rec[row];
    int i1 = __float_as_int(rec.z);
    int i2 = __float_as_int(rec.w);
    float s1 = rec.x * scale_s[i1];
    float s2 = rec.y * scale_s[i2];

    int base = g * 4;
    float4 o;
    o.x = (i1 == base + 0) ? s1 : ((i2 == base + 0) ? s2 : 0.0f);
    o.y = (i1 == base + 1) ? s1 : ((i2 == base + 1) ? s2 : 0.0f);
    o.z = (i1 == base + 2) ? s1 : ((i2 == base + 2) ? s2 : 0.0f);
    o.w = (i1 == base + 3) ? s1 : ((i2 == base + 3) ? s2 : 0.0f);

    ((float4*)out)[(size_t)row * 16 + g] = o;
}

// ---------------------------------------------------------------------------
extern "C" void kernel_launch(void* const* d_in, const int* in_sizes, int n_in,
                              void* d_out, int out_size, void* d_ws, size_t ws_size,
                              hipStream_t stream) {
    const float* x  = (const float*)d_in[0];
    const float* wg = (const float*)d_in[1];
    const float* bg = (const float*)d_in[2];
    float* out = (float*)d_out;

    hipLaunchKernelGGL(init_sums, dim3(1), dim3(256), 0, stream);
    hipLaunchKernelGGL(gate_main, dim3(N_TOK / ROWS_PER_BLK), dim3(256), 0, stream,
                       x, wg, bg);
    hipLaunchKernelGGL(scatter_out, dim3(N_TOK / 16), dim3(256), 0, stream, out);
}

// Round 6
// 408.331 us; speedup vs baseline: 1.3206x; 1.3206x over previous
//
#include <hip/hip_runtime.h>
#include <cstdint>

typedef float f32x2 __attribute__((ext_vector_type(2)));
typedef float f32x4 __attribute__((ext_vector_type(4)));

// Problem constants
constexpr int N_TOK = 32768;
constexpr int DIM   = 1024;
constexpr int NEXP  = 64;
constexpr float CAPACITY = 40960.0f;   // int(1.25 * 32768)
constexpr float EPS_DEN  = 1e-6f;

// Persistent device scratch
__device__ float  g_sums[192];   // [0..63]=denom, [64..127]=importance, [128..191]=load
__device__ float4 g_rec[N_TOK];  // per-row: {raw1, raw2, idx1, idx2}

__global__ void init_sums() {
    if (threadIdx.x < 192) g_sums[threadIdx.x] = 0.0f;
}

// ---------------------------------------------------------------------------
// gate_main: lane = token (64 tokens/block), wave = k-quarter (wave-uniform!).
//   W addresses are wave-uniform -> scalar-pipe s_load broadcast (zero
//   VALU/LDS cost). x: per-lane VMEM, one 64B line per lane per iter,
//   prefetched 1 chunk ahead. Cross-wave K-combine via 64KB LDS, wave-0
//   epilogue (lane-local softmax/top-2; importance via LDS transpose).
//   grid = 512 blocks, 2 blocks/CU (LDS 64.75KB, VGPR ~110).
// ---------------------------------------------------------------------------
__global__ __launch_bounds__(256, 2)
void gate_main(const float* __restrict__ x,
               const float* __restrict__ wg,
               const float* __restrict__ bg) {
    __shared__ float acT[NEXP * 4 * 64];   // [e][q][t]  = 64 KB
    __shared__ float ws[192];

    const int tid  = threadIdx.x;
    const int lane = tid & 63;                                   // token slot
    const int q    = __builtin_amdgcn_readfirstlane(tid >> 6);   // k-quarter
    const int row  = blockIdx.x * 64 + lane;

    if (tid < 192) ws[tid] = 0.0f;

    float acc[NEXP];
#pragma unroll
    for (int e = 0; e < NEXP; ++e) acc[e] = 0.0f;

    const float* xq = x  + (size_t)row * DIM + q * 256;  // per-lane
    const float* wq = wg + q * 256;                      // wave-uniform

    f32x4 xa0, xa1, xa2, xa3;
    {
        const f32x4* xp = (const f32x4*)xq;
        xa0 = xp[0]; xa1 = xp[1]; xa2 = xp[2]; xa3 = xp[3];
    }

#pragma unroll 1
    for (int kc = 0; kc < 16; ++kc) {
        f32x4 xb0, xb1, xb2, xb3;
        if (kc + 1 < 16) {             // prefetch next 64B line (in flight
            const f32x4* xp = (const f32x4*)(xq + (kc + 1) * 16);
            xb0 = xp[0]; xb1 = xp[1]; xb2 = xp[2]; xb3 = xp[3];
        }
#pragma unroll
        for (int e = 0; e < NEXP; ++e) {
            const f32x4* wp = (const f32x4*)(wq + e * DIM + kc * 16);
            f32x4 w0 = wp[0], w1 = wp[1], w2 = wp[2], w3 = wp[3];
            f32x2 t = {0.0f, 0.0f};
            t = __builtin_elementwise_fma((f32x2){xa0.x, xa0.y}, (f32x2){w0.x, w0.y}, t);
            t = __builtin_elementwise_fma((f32x2){xa0.z, xa0.w}, (f32x2){w0.z, w0.w}, t);
            t = __builtin_elementwise_fma((f32x2){xa1.x, xa1.y}, (f32x2){w1.x, w1.y}, t);
            t = __builtin_elementwise_fma((f32x2){xa1.z, xa1.w}, (f32x2){w1.z, w1.w}, t);
            t = __builtin_elementwise_fma((f32x2){xa2.x, xa2.y}, (f32x2){w2.x, w2.y}, t);
            t = __builtin_elementwise_fma((f32x2){xa2.z, xa2.w}, (f32x2){w2.z, w2.w}, t);
            t = __builtin_elementwise_fma((f32x2){xa3.x, xa3.y}, (f32x2){w3.x, w3.y}, t);
            t = __builtin_elementwise_fma((f32x2){xa3.z, xa3.w}, (f32x2){w3.z, w3.w}, t);
            acc[e] += t.x + t.y;
        }
        xa0 = xb0; xa1 = xb1; xa2 = xb2; xa3 = xb3;
    }

    // ---- cross-wave combine: write partials; conflict-free both sides ----
#pragma unroll
    for (int e = 0; e < NEXP; ++e)
        acT[(e * 4 + q) * 64 + lane] = acc[e];
    __syncthreads();

    if (q == 0) {
        // lane = token: gather 4 quarters per expert (consecutive across lanes)
        float lg[NEXP];
#pragma unroll
        for (int e = 0; e < NEXP; ++e) {
            lg[e] = (acT[(e * 4 + 0) * 64 + lane] + acT[(e * 4 + 1) * 64 + lane])
                  + (acT[(e * 4 + 2) * 64 + lane] + acT[(e * 4 + 3) * 64 + lane]);
            lg[e] += bg[e];
        }

        // lane-local top-2 (earliest index on ties, matches lax.top_k)
        float b1 = -INFINITY, b2 = -INFINITY; int i1 = 0, i2 = 0;
#pragma unroll
        for (int e = 0; e < NEXP; ++e) {
            float v = lg[e];
            if (v > b1)      { b2 = b1; i2 = i1; b1 = v; i1 = e; }
            else if (v > b2) { b2 = v;  i2 = e; }
        }

        // lane-local softmax
        float s = 0.0f;
#pragma unroll
        for (int e = 0; e < NEXP; ++e) {
            float t = expf(lg[e] - b1);
            lg[e] = t;
            s += t;
        }
        const float inv  = 1.0f / s;
        const float raw1 = inv;                    // exp(b1-b1)/s
        const float raw2 = expf(b2 - b1) * inv;    // == raw[i2], static recompute

        // importance: transpose through padded LDS (reuse acT; same-wave
        // in-order DS ops make write->read safe without a barrier)
        float* rawT = acT;                         // [t][65]
#pragma unroll
        for (int e = 0; e < NEXP; ++e)
            rawT[lane * 65 + e] = lg[e] * inv;
        __asm__ volatile("" ::: "memory");
        float imp = 0.0f;
#pragma unroll
        for (int t = 0; t < 64; ++t)
            imp += rawT[t * 65 + lane];            // consecutive across lanes
        atomicAdd(&g_sums[64 + lane], imp);

        // denom / load (LDS atomics, scattered) + per-token record
        atomicAdd(&ws[i1], raw1);
        atomicAdd(&ws[i2], raw2);
        atomicAdd(&ws[128 + i1], 1.0f);
        atomicAdd(&ws[128 + i2], 1.0f);
        g_rec[row] = make_float4(raw1, raw2,
                                 __int_as_float(i1), __int_as_float(i2));
    }

    __syncthreads();
    if (tid < 64)                     atomicAdd(&g_sums[tid], ws[tid]);
    else if (tid >= 128 && tid < 192) atomicAdd(&g_sums[tid], ws[tid]);
}

// ---------------------------------------------------------------------------
// finalize + scatter: scale[e]=capacity/(denom+eps); block 0 emits aux loss.
// 16 threads/row, one float4 store each (coalesced); 16 rows/block.
// ---------------------------------------------------------------------------
__global__ __launch_bounds__(256)
void scatter_out(float* __restrict__ out) {
    __shared__ float scale_s[NEXP];
    int tid = threadIdx.x;
    if (tid < NEXP) {
        float den = g_sums[tid];
        scale_s[tid] = CAPACITY / (den + EPS_DEN);
        if (blockIdx.x == 0) {
            float prod = g_sums[64 + tid] * g_sums[128 + tid];
#pragma unroll
            for (int off = 32; off; off >>= 1) prod += __shfl_xor(prod, off);
            if (tid == 0) {
                // aux = 0.01 * mean_e(impSum*loadSum / N^2) * 64^2
                out[(size_t)N_TOK * NEXP] =
                    0.64f * prod / ((float)N_TOK * (float)N_TOK);
            }
        }
    }
    __syncthreads();

    int row = blockIdx.x * 16 + (tid >> 4);
    int g   = tid & 15;

    float4 rec = g_rec[row];
    int i1 = __float_as_int(rec.z);
    int i2 = __float_as_int(rec.w);
    float s1 = rec.x * scale_s[i1];
    float s2 = rec.y * scale_s[i2];

    int base = g * 4;
    float4 o;
    o.x = (i1 == base + 0) ? s1 : ((i2 == base + 0) ? s2 : 0.0f);
    o.y = (i1 == base + 1) ? s1 : ((i2 == base + 1) ? s2 : 0.0f);
    o.z = (i1 == base + 2) ? s1 : ((i2 == base + 2) ? s2 : 0.0f);
    o.w = (i1 == base + 3) ? s1 : ((i2 == base + 3) ? s2 : 0.0f);

    ((float4*)out)[(size_t)row * 16 + g] = o;
}

// ---------------------------------------------------------------------------
extern "C" void kernel_launch(void* const* d_in, const int* in_sizes, int n_in,
                              void* d_out, int out_size, void* d_ws, size_t ws_size,
                              hipStream_t stream) {
    const float* x  = (const float*)d_in[0];
    const float* wg = (const float*)d_in[1];
    const float* bg = (const float*)d_in[2];
    float* out = (float*)d_out;

    hipLaunchKernelGGL(init_sums, dim3(1), dim3(256), 0, stream);
    hipLaunchKernelGGL(gate_main, dim3(N_TOK / 64), dim3(256), 0, stream,
                       x, wg, bg);
    hipLaunchKernelGGL(scatter_out, dim3(N_TOK / 16), dim3(256), 0, stream, out);
}